// Round 1
// baseline (312.352 us; speedup 1.0000x reference)
//
#include <hip/hip_runtime.h>

// GQA forward: emb-gather -> K/V/Q projections -> flash attention -> out proj.
// All GEMMs bf16 MFMA 16x16x32, fp32 accumulate.
// ws layout (bf16/ushort elems): e[2048*2048] K[2048*512] V[2048*512] Q[2048*2048] Ctx[2048*2048] = 28 MB.

typedef __bf16 bf16x8 __attribute__((ext_vector_type(8)));
typedef float f32x4 __attribute__((ext_vector_type(4)));
typedef unsigned short ushort8_t __attribute__((ext_vector_type(8)));

#define DEVI static __device__ __forceinline__

DEVI unsigned short f2bf(float f) {
    union { float f; unsigned int u; } c; c.f = f;
    unsigned int u = c.u;
    unsigned int r = (u + 0x7FFFu + ((u >> 16) & 1u)) >> 16;  // RNE
    return (unsigned short)r;
}

DEVI f32x4 mfma16(bf16x8 a, bf16x8 b, f32x4 c) {
    return __builtin_amdgcn_mfma_f32_16x16x32_bf16(a, b, c, 0, 0, 0);
}

#define LDT 72  // padded LDS row length (elems): 144 B stride = 36 banks -> 2-way (free)

__global__ __launch_bounds__(256)
void gather_cast_k(const int* __restrict__ X, const float* __restrict__ emb,
                   unsigned short* __restrict__ e) {
    int s = blockIdx.x;
    long long row = X[s];
    const float* src = emb + row * 2048 + threadIdx.x * 8;
    float4 f0 = *(const float4*)(src);
    float4 f1 = *(const float4*)(src + 4);
    ushort8_t v;
    v[0] = f2bf(f0.x); v[1] = f2bf(f0.y); v[2] = f2bf(f0.z); v[3] = f2bf(f0.w);
    v[4] = f2bf(f1.x); v[5] = f2bf(f1.y); v[6] = f2bf(f1.z); v[7] = f2bf(f1.w);
    *(ushort8_t*)(e + (size_t)s * 2048 + threadIdx.x * 8) = v;
}

// C[m][n] = sum_k A[m][k] * W[n][k].  A: bf16 [M][K] (lda=K). W: fp32 [N][K], cvt on the fly.
// blockIdx.y >= nsplit selects the second (W2,C2) problem (used to fuse K+V projections).
// OUTMODE 0: bf16 out;  OUTMODE 1: f32 out + bias.
template<int OUTMODE>
__global__ __launch_bounds__(256)
void gemm_bt_k(const unsigned short* __restrict__ A,
               const float* __restrict__ W, const float* __restrict__ W2,
               void* __restrict__ C, void* __restrict__ C2, int nsplit,
               const float* __restrict__ bias, int K, int ldc) {
    __shared__ unsigned short As[128 * LDT];
    __shared__ unsigned short Ws[128 * LDT];
    int by = blockIdx.y;
    const float* Wp = W;
    void* Cp = C;
    if (by >= nsplit) { Wp = W2; Cp = C2; by -= nsplit; }
    const int m0 = blockIdx.x * 128;
    const int n0 = by * 128;
    const int tid = threadIdx.x;
    const int lane = tid & 63;
    const int w = tid >> 6;
    const int wm = (w >> 1) * 64, wn = (w & 1) * 64;
    const int lr = lane & 15, lg = lane >> 4;

    f32x4 acc[4][4];
    #pragma unroll
    for (int i = 0; i < 4; i++)
        #pragma unroll
        for (int j = 0; j < 4; j++) acc[i][j] = {};

    for (int k0 = 0; k0 < K; k0 += 64) {
        #pragma unroll
        for (int i = 0; i < 4; i++) {
            int chunk = tid + i * 256;
            int row = chunk >> 3, cc = chunk & 7;
            ushort8_t va = *(const ushort8_t*)(A + (size_t)(m0 + row) * K + k0 + cc * 8);
            *(ushort8_t*)(&As[row * LDT + cc * 8]) = va;
            const float* wp = Wp + (size_t)(n0 + row) * K + k0 + cc * 8;
            float4 g0 = *(const float4*)(wp);
            float4 g1 = *(const float4*)(wp + 4);
            ushort8_t vw;
            vw[0] = f2bf(g0.x); vw[1] = f2bf(g0.y); vw[2] = f2bf(g0.z); vw[3] = f2bf(g0.w);
            vw[4] = f2bf(g1.x); vw[5] = f2bf(g1.y); vw[6] = f2bf(g1.z); vw[7] = f2bf(g1.w);
            *(ushort8_t*)(&Ws[row * LDT + cc * 8]) = vw;
        }
        __syncthreads();
        #pragma unroll
        for (int kk = 0; kk < 2; kk++) {
            bf16x8 af[4], bfr[4];
            #pragma unroll
            for (int mi = 0; mi < 4; mi++)
                af[mi] = *(const bf16x8*)(&As[(wm + mi * 16 + lr) * LDT + kk * 32 + lg * 8]);
            #pragma unroll
            for (int ni = 0; ni < 4; ni++)
                bfr[ni] = *(const bf16x8*)(&Ws[(wn + ni * 16 + lr) * LDT + kk * 32 + lg * 8]);
            #pragma unroll
            for (int mi = 0; mi < 4; mi++)
                #pragma unroll
                for (int ni = 0; ni < 4; ni++)
                    acc[mi][ni] = mfma16(af[mi], bfr[ni], acc[mi][ni]);
        }
        __syncthreads();
    }
    #pragma unroll
    for (int mi = 0; mi < 4; mi++)
        #pragma unroll
        for (int ni = 0; ni < 4; ni++) {
            int col = n0 + wn + ni * 16 + lr;
            #pragma unroll
            for (int jj = 0; jj < 4; jj++) {
                int rowg = m0 + wm + mi * 16 + lg * 4 + jj;
                float vv = acc[mi][ni][jj];
                if (OUTMODE == 0) {
                    ((unsigned short*)Cp)[(size_t)rowg * ldc + col] = f2bf(vv);
                } else {
                    ((float*)Cp)[(size_t)rowg * ldc + col] = vv + bias[col];
                }
            }
        }
}

// Flash attention. Grid: 1024 = 32 q-heads x 32 q-tiles(64 rows). 4 waves x 16 q-rows.
// K LDS [t][dk], V LDS transposed [dk][t], P per-wave LDS for layout change.
__global__ __launch_bounds__(256)
void attn_k(const unsigned short* __restrict__ Qb, const unsigned short* __restrict__ Kb,
            const unsigned short* __restrict__ Vb, unsigned short* __restrict__ Ctx) {
    __shared__ unsigned short Ks[64 * LDT];
    __shared__ unsigned short Vt[64 * LDT];
    __shared__ unsigned short Ps[4 * 16 * LDT];
    const int hq = blockIdx.x & 31;
    const int qt = blockIdx.x >> 5;
    const int ikv = hq >> 2;
    const int tid = threadIdx.x, lane = tid & 63, w = tid >> 6;
    const int lr = lane & 15, lg = lane >> 4;
    const int q0 = qt * 64 + w * 16;
    const float LOG2E = 1.4426950408889634f;

    bf16x8 qf[2];
    #pragma unroll
    for (int kk = 0; kk < 2; kk++)
        qf[kk] = *(const bf16x8*)(Qb + (size_t)(q0 + lr) * 2048 + hq * 64 + kk * 32 + lg * 8);

    f32x4 acc[4];
    #pragma unroll
    for (int nd = 0; nd < 4; nd++) acc[nd] = {};
    float mrow[4], lrow[4];
    #pragma unroll
    for (int jj = 0; jj < 4; jj++) { mrow[jj] = -1e30f; lrow[jj] = 0.0f; }

    const int vrow = tid >> 2, vdk = (tid & 3) * 16;

    for (int t0 = 0; t0 < 2048; t0 += 64) {
        // stage K tile [64][64]
        #pragma unroll
        for (int i = 0; i < 2; i++) {
            int chunk = tid + i * 256;
            int row = chunk >> 3, cc = chunk & 7;
            ushort8_t v = *(const ushort8_t*)(Kb + (size_t)(t0 + row) * 512 + ikv * 64 + cc * 8);
            *(ushort8_t*)(&Ks[row * LDT + cc * 8]) = v;
        }
        // stage V transposed [dk][t]
        {
            const unsigned short* vp = Vb + (size_t)(t0 + vrow) * 512 + ikv * 64 + vdk;
            ushort8_t v0 = *(const ushort8_t*)(vp);
            ushort8_t v1 = *(const ushort8_t*)(vp + 8);
            #pragma unroll
            for (int jj = 0; jj < 8; jj++) Vt[(vdk + jj) * LDT + vrow] = v0[jj];
            #pragma unroll
            for (int jj = 0; jj < 8; jj++) Vt[(vdk + 8 + jj) * LDT + vrow] = v1[jj];
        }
        __syncthreads();

        // S = Q K^T
        f32x4 s[4];
        #pragma unroll
        for (int nd = 0; nd < 4; nd++) s[nd] = {};
        #pragma unroll
        for (int nd = 0; nd < 4; nd++)
            #pragma unroll
            for (int kk = 0; kk < 2; kk++) {
                bf16x8 kf = *(const bf16x8*)(&Ks[(nd * 16 + lr) * LDT + kk * 32 + lg * 8]);
                s[nd] = mfma16(qf[kk], kf, s[nd]);
            }
        #pragma unroll
        for (int nd = 0; nd < 4; nd++) s[nd] *= 0.125f;

        // online softmax (rows live at lg*4+jj, cols at nd*16+lr)
        #pragma unroll
        for (int jj = 0; jj < 4; jj++) {
            float mx = fmaxf(fmaxf(s[0][jj], s[1][jj]), fmaxf(s[2][jj], s[3][jj]));
            #pragma unroll
            for (int off = 1; off < 16; off <<= 1)
                mx = fmaxf(mx, __shfl_xor(mx, off, 64));
            float mnew = fmaxf(mrow[jj], mx);
            float sc = exp2f((mrow[jj] - mnew) * LOG2E);
            mrow[jj] = mnew;
            float rs = 0.0f;
            #pragma unroll
            for (int nd = 0; nd < 4; nd++) {
                float p = exp2f((s[nd][jj] - mnew) * LOG2E);
                s[nd][jj] = p;
                rs += p;
            }
            #pragma unroll
            for (int off = 1; off < 16; off <<= 1)
                rs += __shfl_xor(rs, off, 64);
            lrow[jj] = lrow[jj] * sc + rs;
            #pragma unroll
            for (int nd = 0; nd < 4; nd++) acc[nd][jj] *= sc;
        }

        // P -> LDS (D-layout) then reload as A-layout
        #pragma unroll
        for (int nd = 0; nd < 4; nd++)
            #pragma unroll
            for (int jj = 0; jj < 4; jj++)
                Ps[w * 16 * LDT + (lg * 4 + jj) * LDT + nd * 16 + lr] = f2bf(s[nd][jj]);
        __syncthreads();

        bf16x8 pa[2];
        #pragma unroll
        for (int kk = 0; kk < 2; kk++)
            pa[kk] = *(const bf16x8*)(&Ps[w * 16 * LDT + lr * LDT + kk * 32 + lg * 8]);
        #pragma unroll
        for (int nd = 0; nd < 4; nd++)
            #pragma unroll
            for (int kk = 0; kk < 2; kk++) {
                bf16x8 vf = *(const bf16x8*)(&Vt[(nd * 16 + lr) * LDT + kk * 32 + lg * 8]);
                acc[nd] = mfma16(pa[kk], vf, acc[nd]);
            }
        __syncthreads();
    }

    #pragma unroll
    for (int nd = 0; nd < 4; nd++)
        #pragma unroll
        for (int jj = 0; jj < 4; jj++) {
            float vv = acc[nd][jj] / lrow[jj];
            Ctx[(size_t)(q0 + lg * 4 + jj) * 2048 + hq * 64 + nd * 16 + lr] = f2bf(vv);
        }
}

extern "C" void kernel_launch(void* const* d_in, const int* in_sizes, int n_in,
                              void* d_out, int out_size, void* d_ws, size_t ws_size,
                              hipStream_t stream) {
    (void)in_sizes; (void)n_in; (void)out_size; (void)ws_size;
    const int*   X   = (const int*)d_in[0];
    const float* emb = (const float*)d_in[1];
    const float* Wk  = (const float*)d_in[2];
    const float* Wv  = (const float*)d_in[3];
    const float* Wq  = (const float*)d_in[4];
    const float* Wo  = (const float*)d_in[5];
    const float* Wb  = (const float*)d_in[6];

    unsigned short* e   = (unsigned short*)d_ws;
    unsigned short* Kb  = e  + (size_t)2048 * 2048;
    unsigned short* Vb  = Kb + (size_t)2048 * 512;
    unsigned short* Qb  = Vb + (size_t)2048 * 512;
    unsigned short* Ctx = Qb + (size_t)2048 * 2048;

    gather_cast_k<<<dim3(2048), dim3(256), 0, stream>>>(X, emb, e);
    // fused K+V projections: by<4 -> Wk->Kb, by>=4 -> Wv->Vb
    gemm_bt_k<0><<<dim3(16, 8), dim3(256), 0, stream>>>(e, Wk, Wv, (void*)Kb, (void*)Vb, 4,
                                                        nullptr, 2048, 512);
    gemm_bt_k<0><<<dim3(16, 16), dim3(256), 0, stream>>>(e, Wq, Wq, (void*)Qb, (void*)Qb, 1 << 30,
                                                         nullptr, 2048, 2048);
    attn_k<<<dim3(1024), dim3(256), 0, stream>>>(Qb, Kb, Vb, Ctx);
    gemm_bt_k<1><<<dim3(16, 16), dim3(256), 0, stream>>>(Ctx, Wo, Wo, d_out, d_out, 1 << 30,
                                                         Wb, 2048, 2048);
}

// Round 2
// 238.346 us; speedup vs baseline: 1.3105x; 1.3105x over previous
//
#include <hip/hip_runtime.h>

// GQA forward: emb-gather -> K/V/Q projections -> flash attention -> out proj.
// Attention v2: swapped-QK^T 32x32x16 MFMA, in-register softmax (cvt_pk +
// permlane32_swap), XOR-swizzled LDS, V^T produced by the V-projection GEMM.
// ws layout (ushort elems): e[2048*2048] K[2048*512] VT[512*2048] Q[2048*2048] Ctx[2048*2048] = 28 MB.

typedef __bf16 bf16x8 __attribute__((ext_vector_type(8)));
typedef float f32x4 __attribute__((ext_vector_type(4)));
typedef float f32x16 __attribute__((ext_vector_type(16)));
typedef unsigned short ushort8_t __attribute__((ext_vector_type(8)));
typedef unsigned int uint4_t __attribute__((ext_vector_type(4)));

#define DEVI static __device__ __forceinline__

DEVI unsigned short f2bf(float f) {
    union { float f; unsigned int u; } c; c.f = f;
    unsigned int u = c.u;
    unsigned int r = (u + 0x7FFFu + ((u >> 16) & 1u)) >> 16;  // RNE
    return (unsigned short)r;
}

DEVI f32x4 mfma16(bf16x8 a, bf16x8 b, f32x4 c) {
    return __builtin_amdgcn_mfma_f32_16x16x32_bf16(a, b, c, 0, 0, 0);
}
DEVI f32x16 mfma32(bf16x8 a, bf16x8 b, f32x16 c) {
    return __builtin_amdgcn_mfma_f32_32x32x16_bf16(a, b, c, 0, 0, 0);
}
DEVI unsigned cvtpk(float a, float b) {
    unsigned r;
    asm("v_cvt_pk_bf16_f32 %0, %1, %2" : "=v"(r) : "v"(a), "v"(b));
    return r;
}
DEVI void plswap(unsigned& a, unsigned& b) {
    asm("v_permlane32_swap_b32 %0, %1" : "+v"(a), "+v"(b));
}

#define LDT 72  // gemm LDS pad

__global__ __launch_bounds__(256)
void gather_cast_k(const int* __restrict__ X, const float* __restrict__ emb,
                   unsigned short* __restrict__ e) {
    int s = blockIdx.x;
    long long row = X[s];
    const float* src = emb + row * 2048 + threadIdx.x * 8;
    float4 f0 = *(const float4*)(src);
    float4 f1 = *(const float4*)(src + 4);
    ushort8_t v;
    v[0] = f2bf(f0.x); v[1] = f2bf(f0.y); v[2] = f2bf(f0.z); v[3] = f2bf(f0.w);
    v[4] = f2bf(f1.x); v[5] = f2bf(f1.y); v[6] = f2bf(f1.z); v[7] = f2bf(f1.w);
    *(ushort8_t*)(e + (size_t)s * 2048 + threadIdx.x * 8) = v;
}

// C[m][n] = sum_k A[m][k] * W[n][k].  A: bf16 [M][K]. W: fp32 [N][K] cvt on the fly.
// by >= nsplit selects (W2,C2,ldc2,om2). omode: 0 bf16 row-major; 1 f32+bias; 2 bf16 TRANSPOSED.
__global__ __launch_bounds__(256)
void gemm_bt_k(const unsigned short* __restrict__ A,
               const float* __restrict__ W, const float* __restrict__ W2,
               void* __restrict__ C, void* __restrict__ C2, int nsplit,
               const float* __restrict__ bias, int K,
               int ldc1, int ldc2, int om1, int om2) {
    __shared__ unsigned short As[128 * LDT];
    __shared__ unsigned short Ws[128 * LDT];
    int by = blockIdx.y;
    const float* Wp = W;
    void* Cp = C;
    int ldc = ldc1, omode = om1;
    if (by >= nsplit) { Wp = W2; Cp = C2; ldc = ldc2; omode = om2; by -= nsplit; }
    const int m0 = blockIdx.x * 128;
    const int n0 = by * 128;
    const int tid = threadIdx.x;
    const int lane = tid & 63;
    const int w = tid >> 6;
    const int wm = (w >> 1) * 64, wn = (w & 1) * 64;
    const int lr = lane & 15, lg = lane >> 4;

    f32x4 acc[4][4];
    #pragma unroll
    for (int i = 0; i < 4; i++)
        #pragma unroll
        for (int j = 0; j < 4; j++) acc[i][j] = {};

    for (int k0 = 0; k0 < K; k0 += 64) {
        #pragma unroll
        for (int i = 0; i < 4; i++) {
            int chunk = tid + i * 256;
            int row = chunk >> 3, cc = chunk & 7;
            ushort8_t va = *(const ushort8_t*)(A + (size_t)(m0 + row) * K + k0 + cc * 8);
            *(ushort8_t*)(&As[row * LDT + cc * 8]) = va;
            const float* wp = Wp + (size_t)(n0 + row) * K + k0 + cc * 8;
            float4 g0 = *(const float4*)(wp);
            float4 g1 = *(const float4*)(wp + 4);
            ushort8_t vw;
            vw[0] = f2bf(g0.x); vw[1] = f2bf(g0.y); vw[2] = f2bf(g0.z); vw[3] = f2bf(g0.w);
            vw[4] = f2bf(g1.x); vw[5] = f2bf(g1.y); vw[6] = f2bf(g1.z); vw[7] = f2bf(g1.w);
            *(ushort8_t*)(&Ws[row * LDT + cc * 8]) = vw;
        }
        __syncthreads();
        #pragma unroll
        for (int kk = 0; kk < 2; kk++) {
            bf16x8 af[4], bfr[4];
            #pragma unroll
            for (int mi = 0; mi < 4; mi++)
                af[mi] = *(const bf16x8*)(&As[(wm + mi * 16 + lr) * LDT + kk * 32 + lg * 8]);
            #pragma unroll
            for (int ni = 0; ni < 4; ni++)
                bfr[ni] = *(const bf16x8*)(&Ws[(wn + ni * 16 + lr) * LDT + kk * 32 + lg * 8]);
            #pragma unroll
            for (int mi = 0; mi < 4; mi++)
                #pragma unroll
                for (int ni = 0; ni < 4; ni++)
                    acc[mi][ni] = mfma16(af[mi], bfr[ni], acc[mi][ni]);
        }
        __syncthreads();
    }
    #pragma unroll
    for (int mi = 0; mi < 4; mi++)
        #pragma unroll
        for (int ni = 0; ni < 4; ni++) {
            int col = n0 + wn + ni * 16 + lr;
            #pragma unroll
            for (int jj = 0; jj < 4; jj++) {
                int rowg = m0 + wm + mi * 16 + lg * 4 + jj;
                float vv = acc[mi][ni][jj];
                if (omode == 0) {
                    ((unsigned short*)Cp)[(size_t)rowg * ldc + col] = f2bf(vv);
                } else if (omode == 1) {
                    ((float*)Cp)[(size_t)rowg * ldc + col] = vv + bias[col];
                } else {
                    ((unsigned short*)Cp)[(size_t)col * ldc + rowg] = f2bf(vv);
                }
            }
        }
}

// Flash attention v2. Grid: 512 = 32 heads x 16 q-tiles(128 rows). 4 waves x 32 q-rows.
// Swapped QK^T (mfma(K,Q) -> S^T), per-lane q-row softmax, in-register P repack.
// K LDS [kt][64] and V^T LDS [d][64], both XOR-swizzled on 16B granules.
__global__ __launch_bounds__(256)
void attn2_k(const unsigned short* __restrict__ Qb, const unsigned short* __restrict__ Kb,
             const unsigned short* __restrict__ VbT, unsigned short* __restrict__ Ctx) {
    __shared__ unsigned short Ks[64 * 64];
    __shared__ unsigned short Vts[64 * 64];
    const int hq = blockIdx.x & 31;
    const int qt = blockIdx.x >> 5;
    const int ikv = hq >> 2;
    const int tid = threadIdx.x, lane = tid & 63, w = tid >> 6;
    const int l31 = lane & 31, hi = lane >> 5;
    const int qrow = qt * 128 + w * 32 + l31;
    const float CS = 0.125f * 1.44269504088896f;  // 1/sqrt(64) * log2(e)

    // Q fragments (B-operand): row q = lane&31, k = ks*16 + hi*8 + e
    bf16x8 qf[4];
    #pragma unroll
    for (int ks = 0; ks < 4; ks++)
        qf[ks] = *(const bf16x8*)(Qb + (size_t)qrow * 2048 + hq * 64 + ks * 16 + hi * 8);

    f32x16 oacc0 = {}, oacc1 = {};
    float m = -1e30f, l = 0.0f;

    const int srow = tid >> 3, scc = tid & 7;  // staging: thread -> (row, 16B-chunk)

    for (int t0 = 0; t0 < 2048; t0 += 64) {
        // stage K [64 kt][64 dk] and V^T [64 d][64 t], XOR-swizzled granules
        #pragma unroll
        for (int i = 0; i < 2; i++) {
            int row = srow + i * 32;
            int g = (scc ^ (row & 7)) * 8;
            *(ushort8_t*)(&Ks[row * 64 + g]) =
                *(const ushort8_t*)(Kb + (size_t)(t0 + row) * 512 + ikv * 64 + scc * 8);
            *(ushort8_t*)(&Vts[row * 64 + g]) =
                *(const ushort8_t*)(VbT + (size_t)(ikv * 64 + row) * 2048 + t0 + scc * 8);
        }
        __syncthreads();

        // S^T = K Q^T : rows kt (2 groups of 32), cols q
        f32x16 s0 = {}, s1 = {};
        #pragma unroll
        for (int ks = 0; ks < 4; ks++) {
            int gr = (2 * ks + hi) ^ (l31 & 7);
            bf16x8 kf0 = *(const bf16x8*)(&Ks[l31 * 64 + gr * 8]);
            bf16x8 kf1 = *(const bf16x8*)(&Ks[(32 + l31) * 64 + gr * 8]);
            s0 = mfma32(kf0, qf[ks], s0);
            s1 = mfma32(kf1, qf[ks], s1);
        }

        // online softmax: lane owns q = l31; kt spread over 32 regs + partner lane
        float pmax = s0[0];
        #pragma unroll
        for (int r = 1; r < 16; r++) pmax = fmaxf(pmax, s0[r]);
        #pragma unroll
        for (int r = 0; r < 16; r++) pmax = fmaxf(pmax, s1[r]);
        pmax = fmaxf(pmax, __shfl_xor(pmax, 32, 64));
        pmax *= CS;

        if (!__all(pmax <= m + 8.0f)) {
            float mnew = fmaxf(m, pmax);
            float sc = exp2f(m - mnew);
            m = mnew;
            l *= sc;
            #pragma unroll
            for (int r = 0; r < 16; r++) {
                const int qp = (r & 3) + 8 * (r >> 2);
                float scv = __shfl(sc, qp + 4 * hi, 64);
                oacc0[r] *= scv;
                oacc1[r] *= scv;
            }
        }

        float rs = 0.0f;
        #pragma unroll
        for (int r = 0; r < 16; r++) {
            float p = exp2f(__builtin_fmaf(s0[r], CS, -m));
            s0[r] = p; rs += p;
        }
        #pragma unroll
        for (int r = 0; r < 16; r++) {
            float p = exp2f(__builtin_fmaf(s1[r], CS, -m));
            s1[r] = p; rs += p;
        }
        rs += __shfl_xor(rs, 32, 64);
        l += rs;

        // pack P -> A-fragments: per 16-kt chunk, cvt_pk pairs + permlane32_swap
        uint4_t pw[4];
        #pragma unroll
        for (int c = 0; c < 2; c++) {
            unsigned a  = cvtpk(s0[8 * c + 0], s0[8 * c + 1]);
            unsigned bb = cvtpk(s0[8 * c + 2], s0[8 * c + 3]);
            unsigned cc2 = cvtpk(s0[8 * c + 4], s0[8 * c + 5]);
            unsigned dd = cvtpk(s0[8 * c + 6], s0[8 * c + 7]);
            plswap(a, cc2); plswap(bb, dd);
            pw[c][0] = a; pw[c][1] = bb; pw[c][2] = cc2; pw[c][3] = dd;
        }
        #pragma unroll
        for (int c = 0; c < 2; c++) {
            unsigned a  = cvtpk(s1[8 * c + 0], s1[8 * c + 1]);
            unsigned bb = cvtpk(s1[8 * c + 2], s1[8 * c + 3]);
            unsigned cc2 = cvtpk(s1[8 * c + 4], s1[8 * c + 5]);
            unsigned dd = cvtpk(s1[8 * c + 6], s1[8 * c + 7]);
            plswap(a, cc2); plswap(bb, dd);
            pw[2 + c][0] = a; pw[2 + c][1] = bb; pw[2 + c][2] = cc2; pw[2 + c][3] = dd;
        }

        // PV: ctx[q][d] += P[q][kt] V[kt][d]; B rows = d from V^T LDS
        #pragma unroll
        for (int ks = 0; ks < 4; ks++) {
            bf16x8 pa = __builtin_bit_cast(bf16x8, pw[ks]);
            int gr = (2 * ks + hi) ^ (l31 & 7);
            bf16x8 vf0 = *(const bf16x8*)(&Vts[l31 * 64 + gr * 8]);
            bf16x8 vf1 = *(const bf16x8*)(&Vts[(32 + l31) * 64 + gr * 8]);
            oacc0 = mfma32(pa, vf0, oacc0);
            oacc1 = mfma32(pa, vf1, oacc1);
        }
        __syncthreads();
    }

    float linv = 1.0f / l;
    #pragma unroll
    for (int r = 0; r < 16; r++) {
        const int qp = (r & 3) + 8 * (r >> 2);
        float lv = __shfl(linv, qp + 4 * hi, 64);
        int row = qt * 128 + w * 32 + qp + 4 * hi;
        Ctx[(size_t)row * 2048 + hq * 64 + l31]      = f2bf(oacc0[r] * lv);
        Ctx[(size_t)row * 2048 + hq * 64 + 32 + l31] = f2bf(oacc1[r] * lv);
    }
}

extern "C" void kernel_launch(void* const* d_in, const int* in_sizes, int n_in,
                              void* d_out, int out_size, void* d_ws, size_t ws_size,
                              hipStream_t stream) {
    (void)in_sizes; (void)n_in; (void)out_size; (void)ws_size;
    const int*   X   = (const int*)d_in[0];
    const float* emb = (const float*)d_in[1];
    const float* Wk  = (const float*)d_in[2];
    const float* Wv  = (const float*)d_in[3];
    const float* Wq  = (const float*)d_in[4];
    const float* Wo  = (const float*)d_in[5];
    const float* Wb  = (const float*)d_in[6];

    unsigned short* e   = (unsigned short*)d_ws;
    unsigned short* Kb  = e   + (size_t)2048 * 2048;
    unsigned short* VbT = Kb  + (size_t)2048 * 512;   // [512][2048] = V^T
    unsigned short* Qb  = VbT + (size_t)512 * 2048;
    unsigned short* Ctx = Qb  + (size_t)2048 * 2048;

    gather_cast_k<<<dim3(2048), dim3(256), 0, stream>>>(X, emb, e);
    // fused K+V projections: by<4 -> Wk->Kb (row-major), by>=4 -> Wv->VbT (transposed)
    gemm_bt_k<<<dim3(16, 8), dim3(256), 0, stream>>>(e, Wk, Wv, (void*)Kb, (void*)VbT, 4,
                                                     nullptr, 2048, 512, 2048, 0, 2);
    gemm_bt_k<<<dim3(16, 16), dim3(256), 0, stream>>>(e, Wq, Wq, (void*)Qb, (void*)Qb, 1 << 30,
                                                      nullptr, 2048, 2048, 2048, 0, 0);
    attn2_k<<<dim3(512), dim3(256), 0, stream>>>(Qb, Kb, VbT, Ctx);
    gemm_bt_k<<<dim3(16, 16), dim3(256), 0, stream>>>(Ctx, Wo, Wo, d_out, d_out, 1 << 30,
                                                      Wb, 2048, 2048, 2048, 1, 1);
}

// Round 3
// 198.542 us; speedup vs baseline: 1.5732x; 1.2005x over previous
//
#include <hip/hip_runtime.h>

// GQA forward: gather -> wconv(bf16) -> fused QKV proj -> flash attn -> out proj.
// GEMMs + attn use global_load_lds(16B) double-buffered LDS with counted vmcnt
// (T3/T4 minimum 2-phase), raw s_barrier. Attention: swapped-QK^T 32x32x16,
// in-register softmax (cvt_pk + permlane32_swap), XOR-swizzled K/V^T LDS via
// pre-swizzled global source (rule 21), XCD-chunked head mapping.
// ws (ushort elems): e[4M] Kb[1M] VbT[1M] Qb[4M] Ctx[4M] Wkb[1M] Wvb[1M] = 32 MB
//   Wqb aliases Ctx (dead until attn), Wob aliases e (dead after QKV gemm).

typedef __bf16 bf16x8 __attribute__((ext_vector_type(8)));
typedef float f32x4 __attribute__((ext_vector_type(4)));
typedef float f32x16 __attribute__((ext_vector_type(16)));
typedef unsigned short ushort8_t __attribute__((ext_vector_type(8)));
typedef unsigned int uint4_t __attribute__((ext_vector_type(4)));

#define DEVI static __device__ __forceinline__

DEVI unsigned short f2bf(float f) {
    union { float f; unsigned int u; } c; c.f = f;
    unsigned int u = c.u;
    unsigned int r = (u + 0x7FFFu + ((u >> 16) & 1u)) >> 16;  // RNE
    return (unsigned short)r;
}

DEVI f32x4 mfma16(bf16x8 a, bf16x8 b, f32x4 c) {
    return __builtin_amdgcn_mfma_f32_16x16x32_bf16(a, b, c, 0, 0, 0);
}
DEVI f32x16 mfma32(bf16x8 a, bf16x8 b, f32x16 c) {
    return __builtin_amdgcn_mfma_f32_32x32x16_bf16(a, b, c, 0, 0, 0);
}
DEVI unsigned cvtpk(float a, float b) {
    unsigned r;
    asm("v_cvt_pk_bf16_f32 %0, %1, %2" : "=v"(r) : "v"(a), "v"(b));
    return r;
}
DEVI void plswap(unsigned& a, unsigned& b) {
    asm("v_permlane32_swap_b32 %0, %1" : "+v"(a), "+v"(b));
}
DEVI void gload16(const unsigned short* g, unsigned short* l) {
    __builtin_amdgcn_global_load_lds(
        (const __attribute__((address_space(1))) void*)g,
        (__attribute__((address_space(3))) void*)l, 16, 0, 0);
}
#define WAIT_VM(n) asm volatile("s_waitcnt vmcnt(" #n ")" ::: "memory")
#define WAIT_LGKM0() asm volatile("s_waitcnt lgkmcnt(0)" ::: "memory")
#define BAR() __builtin_amdgcn_s_barrier()

__global__ __launch_bounds__(256)
void gather_cast_k(const int* __restrict__ X, const float* __restrict__ emb,
                   unsigned short* __restrict__ e) {
    int s = blockIdx.x;
    long long row = X[s];
    const float* src = emb + row * 2048 + threadIdx.x * 8;
    float4 f0 = *(const float4*)(src);
    float4 f1 = *(const float4*)(src + 4);
    ushort8_t v;
    v[0] = f2bf(f0.x); v[1] = f2bf(f0.y); v[2] = f2bf(f0.z); v[3] = f2bf(f0.w);
    v[4] = f2bf(f1.x); v[5] = f2bf(f1.y); v[6] = f2bf(f1.z); v[7] = f2bf(f1.w);
    *(ushort8_t*)(e + (size_t)s * 2048 + threadIdx.x * 8) = v;
}

// f32 -> bf16 weight convert, 3 segments by block ranges (counts in 2048-elem blocks)
__global__ __launch_bounds__(256)
void wconv_k(const float* __restrict__ s0, unsigned short* __restrict__ d0, int c0,
             const float* __restrict__ s1, unsigned short* __restrict__ d1, int c1,
             const float* __restrict__ s2, unsigned short* __restrict__ d2) {
    int b = blockIdx.x;
    const float* s; unsigned short* d; int off;
    if (b < c0) { s = s0; d = d0; off = b; }
    else if (b < c0 + c1) { s = s1; d = d1; off = b - c0; }
    else { s = s2; d = d2; off = b - c0 - c1; }
    size_t idx = ((size_t)off * 256 + threadIdx.x) * 8;
    float4 f0 = *(const float4*)(s + idx);
    float4 f1 = *(const float4*)(s + idx + 4);
    ushort8_t v;
    v[0] = f2bf(f0.x); v[1] = f2bf(f0.y); v[2] = f2bf(f0.z); v[3] = f2bf(f0.w);
    v[4] = f2bf(f1.x); v[5] = f2bf(f1.y); v[6] = f2bf(f1.z); v[7] = f2bf(f1.w);
    *(ushort8_t*)(d + idx) = v;
}

// C[m][n] = sum_k A[m][k] * W[n][k], A,W bf16 [*][2048]. 128x128 tile, BK=64,
// double-buffered global_load_lds, counted vmcnt, raw barriers.
// by<t1 -> seg0, by<t2 -> seg1, else seg2. om: 0 bf16; 1 f32+bias; 2 bf16 transposed.
__global__ __launch_bounds__(256)
void gemm_p2_k(const unsigned short* __restrict__ A,
               const unsigned short* __restrict__ W0, const unsigned short* __restrict__ W1,
               const unsigned short* __restrict__ W2,
               void* __restrict__ C0, void* __restrict__ C1, void* __restrict__ C2,
               int t1, int t2, int ldc0, int ldc1, int ldc2,
               int om0, int om1, int om2, const float* __restrict__ bias) {
    __shared__ unsigned short As[2 * 128 * 64];
    __shared__ unsigned short Bs[2 * 128 * 64];
    const int cpx = gridDim.x >> 3;
    int id = blockIdx.x;
    int swz = (id & 7) * cpx + (id >> 3);
    const int bx = swz & 15;
    const int by = swz >> 4;
    const unsigned short* Wp; void* Cp; int ldc, om, nb;
    if (by < t1)      { Wp = W0; Cp = C0; ldc = ldc0; om = om0; nb = by; }
    else if (by < t2) { Wp = W1; Cp = C1; ldc = ldc1; om = om1; nb = by - t1; }
    else              { Wp = W2; Cp = C2; ldc = ldc2; om = om2; nb = by - t2; }
    const int m0 = bx * 128, n0 = nb * 128;
    const int tid = threadIdx.x, lane = tid & 63, w = tid >> 6;
    const int wm = (w >> 1) * 64, wn = (w & 1) * 64;
    const int lr = lane & 15, lg = lane >> 4;

    f32x4 acc[4][4];
    #pragma unroll
    for (int i = 0; i < 4; i++)
        #pragma unroll
        for (int j = 0; j < 4; j++) acc[i][j] = {};

    const int srow = tid >> 3, sj = tid & 7;  // chunk = tid + i*256

    // stage(buf, k0): 8 x global_load_lds (4 A + 4 W)
    #define G_STAGE(buf, k0)                                                          \
        _Pragma("unroll")                                                             \
        for (int i = 0; i < 4; i++) {                                                 \
            int row = srow + i * 32;                                                  \
            unsigned short* ad = As + (buf) * 8192 + (w * 64 + i * 256) * 8;          \
            unsigned short* bd = Bs + (buf) * 8192 + (w * 64 + i * 256) * 8;          \
            gload16(A  + (size_t)(m0 + row) * 2048 + (k0) + sj * 8, ad);              \
            gload16(Wp + (size_t)(n0 + row) * 2048 + (k0) + sj * 8, bd);              \
        }

    G_STAGE(0, 0);
    for (int s = 0; s < 32; ++s) {
        const int cur = s & 1;
        if (s < 31) {
            G_STAGE(cur ^ 1, (s + 1) * 64);
            WAIT_VM(8);
        } else {
            WAIT_VM(0);
        }
        BAR();
        #pragma unroll
        for (int kk = 0; kk < 2; kk++) {
            bf16x8 af[4], bfr[4];
            #pragma unroll
            for (int mi = 0; mi < 4; mi++)
                af[mi] = *(const bf16x8*)(&As[cur * 8192 + (wm + mi * 16 + lr) * 64 + kk * 32 + lg * 8]);
            #pragma unroll
            for (int ni = 0; ni < 4; ni++)
                bfr[ni] = *(const bf16x8*)(&Bs[cur * 8192 + (wn + ni * 16 + lr) * 64 + kk * 32 + lg * 8]);
            #pragma unroll
            for (int mi = 0; mi < 4; mi++)
                #pragma unroll
                for (int ni = 0; ni < 4; ni++)
                    acc[mi][ni] = mfma16(af[mi], bfr[ni], acc[mi][ni]);
        }
        WAIT_LGKM0();
        BAR();
    }
    #undef G_STAGE

    #pragma unroll
    for (int mi = 0; mi < 4; mi++)
        #pragma unroll
        for (int ni = 0; ni < 4; ni++) {
            int col = n0 + wn + ni * 16 + lr;
            #pragma unroll
            for (int jj = 0; jj < 4; jj++) {
                int rowg = m0 + wm + mi * 16 + lg * 4 + jj;
                float vv = acc[mi][ni][jj];
                if (om == 0) {
                    ((unsigned short*)Cp)[(size_t)rowg * ldc + col] = f2bf(vv);
                } else if (om == 1) {
                    ((float*)Cp)[(size_t)rowg * ldc + col] = vv + bias[col];
                } else {
                    ((unsigned short*)Cp)[(size_t)col * ldc + rowg] = f2bf(vv);
                }
            }
        }
}

// Flash attention. Grid 512 (XCD-chunked: ikv == blockIdx%8). 4 waves x 32 q-rows.
// K/V^T tiles double-buffered via global_load_lds with pre-swizzled source.
__global__ __launch_bounds__(256)
void attn2_k(const unsigned short* __restrict__ Qb, const unsigned short* __restrict__ Kb,
             const unsigned short* __restrict__ VbT, unsigned short* __restrict__ Ctx) {
    __shared__ unsigned short Ks[2 * 64 * 64];
    __shared__ unsigned short Vts[2 * 64 * 64];
    int id = blockIdx.x;
    int swz = (id & 7) * 64 + (id >> 3);   // XCD c owns heads 4c..4c+3 (KV L2-resident)
    const int hq = swz >> 4;
    const int qt = swz & 15;
    const int ikv = hq >> 2;
    const int tid = threadIdx.x, lane = tid & 63, w = tid >> 6;
    const int l31 = lane & 31, hi = lane >> 5;
    const int qrow = qt * 128 + w * 32 + l31;
    const float CS = 0.125f * 1.44269504088896f;  // 1/sqrt(64) * log2(e)

    bf16x8 qf[4];
    #pragma unroll
    for (int ks = 0; ks < 4; ks++)
        qf[ks] = *(const bf16x8*)(Qb + (size_t)qrow * 2048 + hq * 64 + ks * 16 + hi * 8);

    f32x16 oacc0 = {}, oacc1 = {};
    float m = -1e30f, l = 0.0f;

    const int srow = tid >> 3, sj = tid & 7;

    // stage(buf, t0): 4 x global_load_lds (2 K + 2 V), source pre-swizzled j^(row&7)
    #define A_STAGE(buf, t0)                                                          \
        _Pragma("unroll")                                                             \
        for (int i = 0; i < 2; i++) {                                                 \
            int row = srow + i * 32;                                                  \
            int jj = sj ^ (row & 7);                                                  \
            unsigned short* kd = Ks + (buf) * 4096 + (w * 64 + i * 256) * 8;          \
            unsigned short* vd = Vts + (buf) * 4096 + (w * 64 + i * 256) * 8;         \
            gload16(Kb + (size_t)((t0) + row) * 512 + ikv * 64 + jj * 8, kd);         \
            gload16(VbT + (size_t)(ikv * 64 + row) * 2048 + (t0) + jj * 8, vd);       \
        }

    A_STAGE(0, 0);
    for (int t = 0; t < 32; ++t) {
        const int cur = t & 1;
        if (t < 31) {
            A_STAGE(cur ^ 1, (t + 1) * 64);
            WAIT_VM(4);
        } else {
            WAIT_VM(0);
        }
        BAR();

        // S^T = K Q^T
        f32x16 s0 = {}, s1 = {};
        #pragma unroll
        for (int ks = 0; ks < 4; ks++) {
            int gr = (2 * ks + hi) ^ (l31 & 7);
            bf16x8 kf0 = *(const bf16x8*)(&Ks[cur * 4096 + l31 * 64 + gr * 8]);
            bf16x8 kf1 = *(const bf16x8*)(&Ks[cur * 4096 + (32 + l31) * 64 + gr * 8]);
            s0 = mfma32(kf0, qf[ks], s0);
            s1 = mfma32(kf1, qf[ks], s1);
        }

        // online softmax: lane owns q-row l31; kt over 32 regs + partner lane
        float pmax = s0[0];
        #pragma unroll
        for (int r = 1; r < 16; r++) pmax = fmaxf(pmax, s0[r]);
        #pragma unroll
        for (int r = 0; r < 16; r++) pmax = fmaxf(pmax, s1[r]);
        pmax = fmaxf(pmax, __shfl_xor(pmax, 32, 64));
        pmax *= CS;

        if (!__all(pmax <= m + 8.0f)) {
            float mnew = fmaxf(m, pmax);
            float sc = exp2f(m - mnew);
            m = mnew;
            l *= sc;
            #pragma unroll
            for (int r = 0; r < 16; r++) {
                const int qp = (r & 3) + 8 * (r >> 2);
                float scv = __shfl(sc, qp + 4 * hi, 64);
                oacc0[r] *= scv;
                oacc1[r] *= scv;
            }
        }

        float rs = 0.0f;
        #pragma unroll
        for (int r = 0; r < 16; r++) {
            float p = exp2f(__builtin_fmaf(s0[r], CS, -m));
            s0[r] = p; rs += p;
        }
        #pragma unroll
        for (int r = 0; r < 16; r++) {
            float p = exp2f(__builtin_fmaf(s1[r], CS, -m));
            s1[r] = p; rs += p;
        }
        rs += __shfl_xor(rs, 32, 64);
        l += rs;

        // pack P -> A-fragments (cvt_pk + permlane32_swap)
        uint4_t pw[4];
        #pragma unroll
        for (int c = 0; c < 2; c++) {
            unsigned a   = cvtpk(s0[8 * c + 0], s0[8 * c + 1]);
            unsigned bb  = cvtpk(s0[8 * c + 2], s0[8 * c + 3]);
            unsigned cc2 = cvtpk(s0[8 * c + 4], s0[8 * c + 5]);
            unsigned dd  = cvtpk(s0[8 * c + 6], s0[8 * c + 7]);
            plswap(a, cc2); plswap(bb, dd);
            pw[c][0] = a; pw[c][1] = bb; pw[c][2] = cc2; pw[c][3] = dd;
        }
        #pragma unroll
        for (int c = 0; c < 2; c++) {
            unsigned a   = cvtpk(s1[8 * c + 0], s1[8 * c + 1]);
            unsigned bb  = cvtpk(s1[8 * c + 2], s1[8 * c + 3]);
            unsigned cc2 = cvtpk(s1[8 * c + 4], s1[8 * c + 5]);
            unsigned dd  = cvtpk(s1[8 * c + 6], s1[8 * c + 7]);
            plswap(a, cc2); plswap(bb, dd);
            pw[2 + c][0] = a; pw[2 + c][1] = bb; pw[2 + c][2] = cc2; pw[2 + c][3] = dd;
        }

        // PV
        #pragma unroll
        for (int ks = 0; ks < 4; ks++) {
            bf16x8 pa = __builtin_bit_cast(bf16x8, pw[ks]);
            int gr = (2 * ks + hi) ^ (l31 & 7);
            bf16x8 vf0 = *(const bf16x8*)(&Vts[cur * 4096 + l31 * 64 + gr * 8]);
            bf16x8 vf1 = *(const bf16x8*)(&Vts[cur * 4096 + (32 + l31) * 64 + gr * 8]);
            oacc0 = mfma32(pa, vf0, oacc0);
            oacc1 = mfma32(pa, vf1, oacc1);
        }
        WAIT_LGKM0();
        BAR();
    }
    #undef A_STAGE

    float linv = 1.0f / l;
    #pragma unroll
    for (int r = 0; r < 16; r++) {
        const int qp = (r & 3) + 8 * (r >> 2);
        float lv = __shfl(linv, qp + 4 * hi, 64);
        int row = qt * 128 + w * 32 + qp + 4 * hi;
        Ctx[(size_t)row * 2048 + hq * 64 + l31]      = f2bf(oacc0[r] * lv);
        Ctx[(size_t)row * 2048 + hq * 64 + 32 + l31] = f2bf(oacc1[r] * lv);
    }
}

extern "C" void kernel_launch(void* const* d_in, const int* in_sizes, int n_in,
                              void* d_out, int out_size, void* d_ws, size_t ws_size,
                              hipStream_t stream) {
    (void)in_sizes; (void)n_in; (void)out_size; (void)ws_size;
    const int*   X   = (const int*)d_in[0];
    const float* emb = (const float*)d_in[1];
    const float* Wk  = (const float*)d_in[2];
    const float* Wv  = (const float*)d_in[3];
    const float* Wq  = (const float*)d_in[4];
    const float* Wo  = (const float*)d_in[5];
    const float* Wb  = (const float*)d_in[6];

    unsigned short* e   = (unsigned short*)d_ws;
    unsigned short* Kb  = e   + (size_t)2048 * 2048;
    unsigned short* VbT = Kb  + (size_t)2048 * 512;
    unsigned short* Qb  = VbT + (size_t)512 * 2048;
    unsigned short* Ctx = Qb  + (size_t)2048 * 2048;
    unsigned short* Wkb = Ctx + (size_t)2048 * 2048;
    unsigned short* Wvb = Wkb + (size_t)512 * 2048;
    unsigned short* Wqb = Ctx;  // alias: Ctx dead until attn; Wqb dead after QKV gemm
    unsigned short* Wob = e;    // alias: e dead after QKV gemm

    gather_cast_k<<<dim3(2048), dim3(256), 0, stream>>>(X, emb, e);
    wconv_k<<<dim3(3072), dim3(256), 0, stream>>>(Wk, Wkb, 512, Wv, Wvb, 512, Wq, Wqb);
    // fused QKV: by<16 Wq->Qb; by<20 Wk->Kb; else Wv->VbT (transposed)
    gemm_p2_k<<<dim3(384), dim3(256), 0, stream>>>(e, Wqb, Wkb, Wvb,
                                                   (void*)Qb, (void*)Kb, (void*)VbT,
                                                   16, 20, 2048, 512, 2048,
                                                   0, 0, 2, nullptr);
    wconv_k<<<dim3(2048), dim3(256), 0, stream>>>(Wo, Wob, 2048, Wo, Wob, 0, Wo, Wob);
    attn2_k<<<dim3(512), dim3(256), 0, stream>>>(Qb, Kb, VbT, Ctx);
    gemm_p2_k<<<dim3(256), dim3(256), 0, stream>>>(Ctx, Wob, Wob, Wob,
                                                   d_out, d_out, d_out,
                                                   16, 32, 2048, 2048, 2048,
                                                   1, 1, 1, Wb);
}